// Round 4
// baseline (540.400 us; speedup 1.0000x reference)
//
#include <hip/hip_runtime.h>
#include <hip/hip_bf16.h>

#define N_NODES 100000
#define N_EDGES 3200000
#define NBUCK   391          // ceil(100000 / 256) buckets of 256 rows

typedef short v8s __attribute__((ext_vector_type(8)));
typedef float v4f __attribute__((ext_vector_type(4)));

__device__ __forceinline__ unsigned short f2b(float x) {
    __hip_bfloat16 h = __float2bfloat16(x);
    return *reinterpret_cast<unsigned short*>(&h);
}
__device__ __forceinline__ float b2f(unsigned short u) {
    return __uint_as_float(((unsigned int)u) << 16);
}

// async global->LDS, 16B per lane. LDS dest is wave-uniform base + lane*16;
// we XOR-swizzle the GLOBAL side since the LDS side can't be padded.
__device__ __forceinline__ void gld16(const void* g, void* l) {
    __builtin_amdgcn_global_load_lds(
        (const __attribute__((address_space(1))) void*)g,
        (__attribute__((address_space(3))) void*)l, 16, 0, 0);
}

// ---------------------------------------------------------------------------
// Pre-transpose + convert weight: B[k][n] fp32 -> BT[n][k] bf16
// ---------------------------------------------------------------------------
__global__ void transpose_b(const float* __restrict__ B, unsigned short* __restrict__ BT) {
    int n = blockIdx.x;
    int k = threadIdx.x;
    BT[n * 256 + k] = f2b(B[k * 256 + n]);
}

// ---------------------------------------------------------------------------
// GEMM (m97-style): 128x256 tile, 512 threads, BK=64, global_load_lds(16B),
// XOR-swizzled chunk layouts (2-way max bank aliasing under quarter-wave
// phasing -> free per m134/m136).
// ---------------------------------------------------------------------------
__global__ __launch_bounds__(512)
void gemm_dma(const float* __restrict__ A, const unsigned short* __restrict__ BT,
              unsigned short* __restrict__ C) {
    __shared__ __align__(16) float          sA[128 * 64];   // 32 KB
    __shared__ __align__(16) unsigned short sB[256 * 64];   // 32 KB

    const int tid  = threadIdx.x;
    const int wave = tid >> 6;
    const int lane = tid & 63;
    const int quad = lane >> 4;
    const int l16  = lane & 15;
    const int row0 = blockIdx.x * 128;

    v4f acc[16];
#pragma unroll
    for (int t = 0; t < 16; t++) acc[t] = (v4f){0.f, 0.f, 0.f, 0.f};

    const int ml = wave * 16 + l16;            // this lane's A row (local)

    for (int ks = 0; ks < 4; ks++) {
        const int kbase = ks * 64;
        // --- stage A: 128 x 64 fp32 = 2048 x 16B chunks ---
#pragma unroll
        for (int i = 0; i < 4; i++) {
            int s = i * 512 + tid;
            int m = s >> 4;
            int c = (s & 15) ^ (m & 15);
            int row = row0 + m;
            if (row >= N_NODES) row = row0;    // clamp (stores are guarded)
            gld16(A + (size_t)row * 256 + kbase + c * 4, (char*)sA + (size_t)s * 16);
        }
        // --- stage B: 256 x 64 bf16 = 2048 x 16B chunks ---
#pragma unroll
        for (int i = 0; i < 4; i++) {
            int s = i * 512 + tid;
            int n = s >> 3;
            int c = (s & 7) ^ (n & 7);
            gld16(BT + (size_t)n * 256 + kbase + c * 8, (char*)sB + (size_t)s * 16);
        }
        __syncthreads();

#pragma unroll
        for (int sub = 0; sub < 2; sub++) {
            int ca  = sub * 8 + 2 * quad;
            int pa0 = ml * 16 + (ca ^ (ml & 15));
            int pa1 = ml * 16 + ((ca + 1) ^ (ml & 15));
            v4f lo = *(const v4f*)&sA[pa0 * 4];
            v4f hi = *(const v4f*)&sA[pa1 * 4];
            v8s af;
            af[0] = (short)f2b(lo[0]); af[1] = (short)f2b(lo[1]);
            af[2] = (short)f2b(lo[2]); af[3] = (short)f2b(lo[3]);
            af[4] = (short)f2b(hi[0]); af[5] = (short)f2b(hi[1]);
            af[6] = (short)f2b(hi[2]); af[7] = (short)f2b(hi[3]);
            int cb = sub * 4 + quad;
#pragma unroll
            for (int t = 0; t < 16; t++) {
                int n  = t * 16 + l16;
                int pb = n * 8 + (cb ^ (n & 7));
                v8s bf = *(const v8s*)&sB[pb * 8];
                acc[t] = __builtin_amdgcn_mfma_f32_16x16x32_bf16(af, bf, acc[t], 0, 0, 0);
            }
        }
        __syncthreads();
    }

    const int grow_base = row0 + wave * 16 + quad * 4;
#pragma unroll
    for (int t = 0; t < 16; t++) {
#pragma unroll
        for (int r = 0; r < 4; r++) {
            int grow = grow_base + r;
            if (grow < N_NODES)
                C[(size_t)grow * 256 + t * 16 + l16] = f2b(acc[t][r]);
        }
    }
}

// ---------------------------------------------------------------------------
// Coarse histogram over 391 buckets (rows >> 8) with LDS pre-aggregation.
// ---------------------------------------------------------------------------
__global__ __launch_bounds__(256)
void bhist_kernel(const int* __restrict__ row, int* __restrict__ ghist) {
    __shared__ int h[NBUCK];
    const int tid = threadIdx.x;
    for (int i = tid; i < NBUCK; i += 256) h[i] = 0;
    __syncthreads();
    const int e0 = blockIdx.x * 4096;
#pragma unroll
    for (int j = 0; j < 16; j++) {
        int e = e0 + j * 256 + tid;
        if (e < N_EDGES) atomicAdd(&h[row[e] >> 8], 1);
    }
    __syncthreads();
    for (int i = tid; i < NBUCK; i += 256)
        if (h[i]) atomicAdd(&ghist[i], h[i]);
}

// Exclusive scan of 391 bucket counts; also initializes the global cursors.
__global__ void bscan_kernel(const int* __restrict__ ghist, int* __restrict__ bbase,
                             int* __restrict__ gcur) {
    __shared__ int s[512];
    const int tid = threadIdx.x;   // 512 threads
    int x = (tid < NBUCK) ? ghist[tid] : 0;
    s[tid] = x;
    __syncthreads();
    for (int off = 1; off < 512; off <<= 1) {
        int v = (tid >= off) ? s[tid - off] : 0;
        __syncthreads();
        s[tid] += v;
        __syncthreads();
    }
    if (tid < NBUCK) {
        int b = s[tid] - x;
        bbase[tid] = b;
        gcur[tid]  = b;
    }
}

// ---------------------------------------------------------------------------
// Bin pass: scatter edges into 391 bucket regions, block-coherent writes.
// Entry: .x = (row_local<<20)|col, .y = fp32 val bits.
// ---------------------------------------------------------------------------
__global__ __launch_bounds__(256)
void bin_kernel(const int* __restrict__ row, const int* __restrict__ col,
                const float* __restrict__ val, int* __restrict__ gcur,
                int2* __restrict__ bucket) {
    __shared__ int lc[NBUCK];
    const int tid = threadIdx.x;
    const int e0 = blockIdx.x * 4096;
    int r[16], c[16];
    float v[16];
#pragma unroll
    for (int j = 0; j < 16; j++) {
        int e = e0 + j * 256 + tid;
        if (e < N_EDGES) { r[j] = row[e]; c[j] = col[e]; v[j] = val[e]; }
        else r[j] = -1;
    }
    for (int i = tid; i < NBUCK; i += 256) lc[i] = 0;
    __syncthreads();
#pragma unroll
    for (int j = 0; j < 16; j++)
        if (r[j] >= 0) atomicAdd(&lc[r[j] >> 8], 1);
    __syncthreads();
    for (int i = tid; i < NBUCK; i += 256) {
        int cnt = lc[i];
        lc[i] = cnt ? atomicAdd(&gcur[i], cnt) : 0;
    }
    __syncthreads();
#pragma unroll
    for (int j = 0; j < 16; j++) {
        if (r[j] >= 0) {
            int b = r[j] >> 8;
            int p = atomicAdd(&lc[b], 1);
            bucket[p] = make_int2(((r[j] & 255) << 20) | c[j], __float_as_int(v[j]));
        }
    }
}

// ---------------------------------------------------------------------------
// Per-bucket counting sort into final CSR (4B packed entries) + offs/counts.
// ---------------------------------------------------------------------------
__global__ __launch_bounds__(256)
void csort_kernel(const int2* __restrict__ bucket, const int* __restrict__ bbase,
                  const int* __restrict__ gcur, unsigned int* __restrict__ csr,
                  int* __restrict__ offs, int* __restrict__ counts) {
    __shared__ int h[256];
    __shared__ int s[256];
    __shared__ int cur[256];
    const int tid  = threadIdx.x;
    const int b    = blockIdx.x;
    const int base = bbase[b];
    const int end  = gcur[b];          // after bin pass: base + bucket size

    h[tid] = 0;
    __syncthreads();
    for (int i = base + tid; i < end; i += 256)
        atomicAdd(&h[bucket[i].x >> 20], 1);
    __syncthreads();

    int x = h[tid];
    s[tid] = x;
    __syncthreads();
    for (int off = 1; off < 256; off <<= 1) {
        int v2 = (tid >= off) ? s[tid - off] : 0;
        __syncthreads();
        s[tid] += v2;
        __syncthreads();
    }
    int ro = s[tid] - x;               // exclusive offset within bucket
    int grow = b * 256 + tid;
    if (grow < N_NODES) {
        offs[grow]   = base + ro;
        counts[grow] = x;
    }
    cur[tid] = base + ro;
    __syncthreads();

    for (int i = base + tid; i < end; i += 256) {
        int2 w = bucket[i];
        int rl = w.x >> 20;
        int p  = atomicAdd(&cur[rl], 1);
        unsigned int vb = (((unsigned int)w.y + 0x8000u) >> 16) & 0x7FFFu;
        csr[p] = (vb << 17) | (unsigned int)(w.x & 0x1FFFF);
    }
}

// ---------------------------------------------------------------------------
// SpMM v3: one wave per row; single shfl of the packed csr word per edge,
// x4 unroll for loads in flight.
// ---------------------------------------------------------------------------
__global__ __launch_bounds__(256)
void spmm_kernel(const unsigned short* __restrict__ sup,
                 const int* __restrict__ offs, const int* __restrict__ counts,
                 const unsigned int* __restrict__ csr, float* __restrict__ out) {
    const int wave = threadIdx.x >> 6;
    const int lane = threadIdx.x & 63;
    const int row  = blockIdx.x * 4 + wave;
    if (row >= N_NODES) return;

    const int start = offs[row];
    const int deg   = counts[row];

    float a0 = 0.f, a1 = 0.f, a2 = 0.f, a3 = 0.f;

    for (int base = 0; base < deg; base += 64) {
        int nb = deg - base;
        if (nb > 64) nb = 64;
        unsigned int w = 0;                 // w==0 -> val bits 0 -> contributes 0
        if (lane < nb) w = csr[start + base + lane];
        int j = 0;
        for (; j + 4 <= nb; j += 4) {
            unsigned int w0 = __shfl(w, j),     w1 = __shfl(w, j + 1);
            unsigned int w2 = __shfl(w, j + 2), w3 = __shfl(w, j + 3);
            int   c0 = (int)(w0 & 0x1FFFFu), c1 = (int)(w1 & 0x1FFFFu);
            int   c2 = (int)(w2 & 0x1FFFFu), c3 = (int)(w3 & 0x1FFFFu);
            float v0 = __uint_as_float((w0 >> 17) << 16);
            float v1 = __uint_as_float((w1 >> 17) << 16);
            float v2 = __uint_as_float((w2 >> 17) << 16);
            float v3 = __uint_as_float((w3 >> 17) << 16);
            ushort4 h0 = *(const ushort4*)(sup + (size_t)c0 * 256 + lane * 4);
            ushort4 h1 = *(const ushort4*)(sup + (size_t)c1 * 256 + lane * 4);
            ushort4 h2 = *(const ushort4*)(sup + (size_t)c2 * 256 + lane * 4);
            ushort4 h3 = *(const ushort4*)(sup + (size_t)c3 * 256 + lane * 4);
            a0 += v0 * b2f(h0.x); a1 += v0 * b2f(h0.y);
            a2 += v0 * b2f(h0.z); a3 += v0 * b2f(h0.w);
            a0 += v1 * b2f(h1.x); a1 += v1 * b2f(h1.y);
            a2 += v1 * b2f(h1.z); a3 += v1 * b2f(h1.w);
            a0 += v2 * b2f(h2.x); a1 += v2 * b2f(h2.y);
            a2 += v2 * b2f(h2.z); a3 += v2 * b2f(h2.w);
            a0 += v3 * b2f(h3.x); a1 += v3 * b2f(h3.y);
            a2 += v3 * b2f(h3.z); a3 += v3 * b2f(h3.w);
        }
        for (; j < nb; j++) {
            unsigned int wj = __shfl(w, j);
            int   cj = (int)(wj & 0x1FFFFu);
            float vj = __uint_as_float((wj >> 17) << 16);
            ushort4 hh = *(const ushort4*)(sup + (size_t)cj * 256 + lane * 4);
            a0 += vj * b2f(hh.x); a1 += vj * b2f(hh.y);
            a2 += vj * b2f(hh.z); a3 += vj * b2f(hh.w);
        }
    }

    float4 o;
    o.x = a0 > 0.f ? a0 : 0.f;
    o.y = a1 > 0.f ? a1 : 0.f;
    o.z = a2 > 0.f ? a2 : 0.f;
    o.w = a3 > 0.f ? a3 : 0.f;
    *(float4*)(out + (size_t)row * 256 + lane * 4) = o;
}

// ---------------------------------------------------------------------------
extern "C" void kernel_launch(void* const* d_in, const int* in_sizes, int n_in,
                              void* d_out, int out_size, void* d_ws, size_t ws_size,
                              hipStream_t stream) {
    const float* features = (const float*)d_in[0];
    const float* weight   = (const float*)d_in[1];
    const int*   adj_row  = (const int*)d_in[2];
    const int*   adj_col  = (const int*)d_in[3];
    const float* adj_val  = (const float*)d_in[4];
    float* out = (float*)d_out;

    char* ws = (char*)d_ws;
    size_t off = 0;
    auto alloc = [&](size_t bytes) -> char* {
        char* p = ws + off;
        off = (off + bytes + 255) & ~(size_t)255;
        return p;
    };
    unsigned short* sup     = (unsigned short*)alloc((size_t)N_NODES * 256 * 2); // 51.2 MB
    unsigned short* BT      = (unsigned short*)alloc(256 * 256 * 2);
    int*            counts  = (int*)alloc((size_t)N_NODES * 4);
    int*            offsets = (int*)alloc((size_t)N_NODES * 4);
    int*            ghist   = (int*)alloc(512 * 4);
    int*            bbase   = (int*)alloc(512 * 4);
    int*            gcur    = (int*)alloc(512 * 4);
    int2*           bucket  = (int2*)alloc((size_t)N_EDGES * 8);                 // 25.6 MB
    unsigned int*   csr     = (unsigned int*)alloc((size_t)N_EDGES * 4);         // 12.8 MB

    hipMemsetAsync(ghist, 0, NBUCK * 4, stream);

    // CSR construction FIRST (streams ~180 MB through L2/L3 before sup exists)
    bhist_kernel<<<782, 256, 0, stream>>>(adj_row, ghist);         // ceil(3.2M/4096)
    bscan_kernel<<<1, 512, 0, stream>>>(ghist, bbase, gcur);
    bin_kernel<<<782, 256, 0, stream>>>(adj_row, adj_col, adj_val, gcur, bucket);
    csort_kernel<<<NBUCK, 256, 0, stream>>>(bucket, bbase, gcur, csr, offsets, counts);

    // GEMM writes sup immediately before spmm consumes it (sup L3/L2-hot)
    transpose_b<<<256, 256, 0, stream>>>(weight, BT);
    gemm_dma<<<782, 512, 0, stream>>>(features, BT, sup);          // ceil(100000/128)
    spmm_kernel<<<25000, 256, 0, stream>>>(sup, offsets, counts, csr, out);
}